// Round 9
// baseline (316.091 us; speedup 1.0000x reference)
//
#include <hip/hip_runtime.h>

// RetinaNet matcher: gt_boxes [B=8, G=64, 4] f32, anchors [A=120000, 4] f32.
// Outputs (concat in d_out, f32): matched_idxs [B,A] (as float), matched_vals [B,A].
//
// Numerics (bit-exact vs np, verified R5-R8 absmax 0.0): opaque() barriers on
// every mul result leave no legal FMA-contraction site -> every op is one
// deterministic IEEE instruction. argmax tie-break = first g (strict >).
// IoU >= 0 -> per-gt max reduces bit-exactly via uint atomicMax.
//
// R9: output-invariant pruning of pass1.
// PROOF: hpg[g] affects outputs only via pu = (q == hpg[g]); pu only changes
// matched_idx when vmax < 0.5 (otherwise m = amax either way). If an anchor
// ties a g with row-max >= 0.5 then its vmax >= 0.5, so that tie never
// matters. Hence ANY stored hpg[g] >= 0.5 (exact or not, racy or not) gives
// bit-identical outputs; hpg[g] < 0.5 is always the exact full max.
// So pass1 waves poll hpg[b,g] (device-scope load) and skip a g entirely
// once some block pushed it >= 0.5 (wave-uniform branch, zero divergence).
// Atomics stream per-g so skips propagate DURING the pass; per-block g-order
// is staggered to decorrelate phases. g's that never reach 0.5 are computed
// fully by every block -> exact (the pu-sensitive case).
// Pass1 shape otherwise = proven R2/R6 partition: 4 anchors/thread,
// 256 pairs/thread, one 6-stage butterfly per g, 1 atomic per wave per g.
// Pass2 + k_init verbatim from R8 (measured ~37 us, absmax 0.0).

static constexpr int G = 64;

__device__ __forceinline__ float opaque(float x) {
    asm volatile("" : "+v"(x));  // no-op; blocks FMA contraction across x
    return x;
}

__device__ __forceinline__ float box_area(float x1, float y1, float x2, float y2) {
    return opaque(__fmul_rn(__fsub_rn(x2, x1), __fsub_rn(y2, y1)));
}

__device__ __forceinline__ float inter_area(float gx1, float gy1, float gx2, float gy2,
                                            float ax1, float ay1, float ax2, float ay2) {
    float ltx = fmaxf(gx1, ax1);
    float lty = fmaxf(gy1, ay1);
    float rbx = fminf(gx2, ax2);
    float rby = fminf(gy2, ay2);
    float w = fmaxf(__fsub_rn(rbx, ltx), 0.0f);
    float h = fmaxf(__fsub_rn(rby, lty), 0.0f);
    return opaque(__fmul_rn(w, h));
}

// hpg[i] = 0 bits (+0.0f) and ga cache for all (b,g).
__global__ void k_init(const float* __restrict__ gt, unsigned int* __restrict__ hpg,
                       float* __restrict__ gab, int BG) {
    int i = blockIdx.x * 256 + threadIdx.x;
    if (i < BG) {
        hpg[i] = 0u;
        float4 gb = ((const float4*)gt)[i];
        gab[i] = box_area(gb.x, gb.y, gb.z, gb.w);
    }
}

// Pass 1: highest_per_gt with >=0.5 skip. Grid: (ceil(A/1024), B), block 256.
// 4 anchors/thread; g-outer; per g: poll -> maybe {4 IoU, 3 fmax, butterfly,
// 1 atomic/wave}.
__global__ __launch_bounds__(256, 8)
void pass1_hpg(const float* __restrict__ gt,
               const float* __restrict__ anchors,
               const float* __restrict__ gab,
               unsigned int* __restrict__ hpg, int A) {
    const int b = blockIdx.y;
    const int t = threadIdx.x;

    // 4 per-lane anchors in registers (degenerate for a >= A -> inter==0, q==+0)
    const int base = blockIdx.x * 1024;
    float ax1[4], ay1[4], ax2[4], ay2[4], aar[4];
#pragma unroll
    for (int k = 0; k < 4; ++k) {
        int a = base + k * 256 + t;
        bool v = (a < A);
        float4 ab = ((const float4*)anchors)[v ? a : 0];
        ax1[k] = v ? ab.x : -3.0e38f;
        ay1[k] = v ? ab.y : -3.0e38f;
        ax2[k] = v ? ab.z : -3.0e38f;
        ay2[k] = v ? ab.w : -3.0e38f;
        aar[k] = box_area(ax1[k], ay1[k], ax2[k], ay2[k]);
    }

    const float4* gtb = (const float4*)gt + (size_t)b * G;
    const float* gas = gab + b * G;
    unsigned int* hb = hpg + b * G;

    const int stag = (int)(blockIdx.x & 63);   // stagger g phase per block
#pragma unroll 1
    for (int gi = 0; gi < G; ++gi) {
        const int g = (gi + stag) & 63;
        // device-scope load; stale values only reduce skipping (monotone max).
        unsigned int cur = __hip_atomic_load(&hb[g], __ATOMIC_RELAXED,
                                             __HIP_MEMORY_SCOPE_AGENT);
        // IoU in [0,1] -> uint bit compare: >= 0.5f  <=>  bits >= 0x3F000000
        if (__builtin_amdgcn_readfirstlane(cur) >= 0x3F000000u) continue;

        const float4 gb = gtb[g];              // uniform -> s_load
        const float ga = gas[g];               // uniform -> s_load
        float m = 0.0f;
#pragma unroll
        for (int k = 0; k < 4; ++k) {
            float inter = inter_area(gb.x, gb.y, gb.z, gb.w,
                                     ax1[k], ay1[k], ax2[k], ay2[k]);
            float denom = __fsub_rn(__fadd_rn(ga, aar[k]), inter);
            float q = __fdiv_rn(inter, denom);
            m = fmaxf(m, q);
        }
#pragma unroll
        for (int st = 0; st < 6; ++st)
            m = fmaxf(m, __shfl_xor(m, 1 << st, 64));
        if ((t & 63) == 0)
            atomicMax(&hb[g], __float_as_uint(m));
    }
}

// Pass 2 (verbatim R8, proven): per anchor -> max/argmax over g, thresholds,
// low-quality recovery. gt/ga/hpg via uniform s_load; anchors per-lane.
// 2 anchors/thread. Grid: (ceil(A/512), B).
__global__ __launch_bounds__(256, 8)
void pass2_match(const float* __restrict__ gt,
                 const float* __restrict__ anchors,
                 const float* __restrict__ gab,
                 const unsigned int* __restrict__ hpg,
                 float* __restrict__ out_idx,
                 float* __restrict__ out_val, int A) {
    const int b = blockIdx.y;
    const int t = threadIdx.x;
    const int base = blockIdx.x * 512;

    float ax1[2], ay1[2], ax2[2], ay2[2], aar[2];
    bool val[2];
#pragma unroll
    for (int k = 0; k < 2; ++k) {
        int a = base + k * 256 + t;
        val[k] = (a < A);
        float4 ab = ((const float4*)anchors)[val[k] ? a : 0];
        ax1[k] = ab.x; ay1[k] = ab.y; ax2[k] = ab.z; ay2[k] = ab.w;
        aar[k] = box_area(ab.x, ab.y, ab.z, ab.w);
    }

    const float4* gtb = (const float4*)gt + (size_t)b * G;
    const float* gas = gab + b * G;
    const unsigned int* hpgb = hpg + b * G;

    // vmax=0/amax=0 start replicates np.argmax on an all-zero row (first idx);
    // strict > keeps the first max thereafter. q >= 0 always.
    float vmax[2] = {0.0f, 0.0f};
    int amax[2] = {0, 0};
    bool pu[2] = {false, false};
#pragma unroll 8
    for (int g = 0; g < G; ++g) {
        float4 gb = gtb[g];                        // uniform -> s_load
        float ga = gas[g];                         // uniform -> s_load
        float hg = __uint_as_float(hpgb[g]);       // uniform -> s_load
#pragma unroll
        for (int k = 0; k < 2; ++k) {
            float inter = inter_area(gb.x, gb.y, gb.z, gb.w,
                                     ax1[k], ay1[k], ax2[k], ay2[k]);
            float denom = __fsub_rn(__fadd_rn(ga, aar[k]), inter);
            float q = __fdiv_rn(inter, denom);
            pu[k] = pu[k] | (q == hg);
            if (q > vmax[k]) { vmax[k] = q; amax[k] = g; }  // first-max tie-break
        }
    }

#pragma unroll
    for (int k = 0; k < 2; ++k) {
        if (!val[k]) continue;
        int m;
        if (pu[k]) {
            m = amax[k];                    // low-quality match recovery
        } else if (vmax[k] < 0.4f) {
            m = -1;                         // BELOW_LOW_QUALITY
        } else if (vmax[k] < 0.5f) {
            m = -2;                         // BETWEEN_THRESHOLDS
        } else {
            m = amax[k];
        }
        size_t o = (size_t)b * A + (base + k * 256 + t);
        out_idx[o] = (float)m;
        out_val[o] = vmax[k];
    }
}

extern "C" void kernel_launch(void* const* d_in, const int* in_sizes, int n_in,
                              void* d_out, int out_size, void* d_ws, size_t ws_size,
                              hipStream_t stream) {
    const float* gt = (const float*)d_in[0];
    const float* anchors = (const float*)d_in[1];
    const int BG = in_sizes[0] / 4;   // B*G = 512
    const int B = BG / G;             // 8
    const int A = in_sizes[1] / 4;    // 120000

    // ws layout (u32 units): [0,512) hpg | [512,1024) ga cache
    unsigned int* hpg = (unsigned int*)d_ws;
    float* gab = (float*)d_ws + 512;

    float* out_idx = (float*)d_out;
    float* out_val = out_idx + (size_t)B * A;

    k_init<<<(BG + 255) / 256, 256, 0, stream>>>(gt, hpg, gab, BG);

    dim3 g1((A + 1023) / 1024, B);
    pass1_hpg<<<g1, 256, 0, stream>>>(gt, anchors, gab, hpg, A);

    dim3 g2((A + 511) / 512, B);
    pass2_match<<<g2, 256, 0, stream>>>(gt, anchors, gab, hpg, out_idx, out_val, A);
}

// Round 10
// 102.651 us; speedup vs baseline: 3.0793x; 3.0793x over previous
//
#include <hip/hip_runtime.h>

// RetinaNet matcher: gt_boxes [B=8, G=64, 4] f32, anchors [A=120000, 4] f32.
// Outputs (concat in d_out, f32): matched_idxs [B,A] (as float), matched_vals [B,A].
//
// Numerics: bit-exact vs np (absmax 0.0 in R5/R6/R8/R9). opaque() barriers on
// every mul result -> no legal FMA-contraction site. argmax tie-break = first
// g (strict >). IoU >= 0 -> per-gt max via uint atomicMax is bit-exact.
//
// R10: counters showed ~59 VALU slots/pair vs ~22 in source; the excess is
// __fdiv_rn's div_scale/div_fmas/div_fixup + VCC hazard dance. div_rn() below
// is the SAME numerical core LLVM emits (rcp, 1 Newton, 2 fma residual
// corrections) minus the scaling scaffolding; power-of-2 scaling is exact and
// our operand ranges are mid-range (no denormal/overflow), so bits are
// identical to v_div = identical to np. 8 slots instead of ~35.
// Pass1 per-g cross-lane max moved from ds_swizzle (DS pipe) to DPP v_max
// (VALU pipe): quad_perm xor1/xor2, row_half_mirror, row_mirror, bcast15,
// bcast31 -> full-wave max valid in lane 63. 1 LDS atomic per g per wave.
// No polling, no sorting, no cross-block traffic (R7/R9 lessons).

static constexpr int G = 64;

__device__ __forceinline__ float opaque(float x) {
    asm volatile("" : "+v"(x));  // no-op; blocks FMA contraction across x
    return x;
}

__device__ __forceinline__ float box_area(float x1, float y1, float x2, float y2) {
    return opaque(__fmul_rn(__fsub_rn(x2, x1), __fsub_rn(y2, y1)));
}

__device__ __forceinline__ float inter_area(float gx1, float gy1, float gx2, float gy2,
                                            float ax1, float ay1, float ax2, float ay2) {
    float ltx = fmaxf(gx1, ax1);
    float lty = fmaxf(gy1, ay1);
    float rbx = fminf(gx2, ax2);
    float rby = fminf(gy2, ay2);
    float w = fmaxf(__fsub_rn(rbx, ltx), 0.0f);
    float h = fmaxf(__fsub_rn(rby, lty), 0.0f);
    return opaque(__fmul_rn(w, h));
}

// Correctly-rounded f32 divide for mid-range operands (no denormal/overflow):
// identical arithmetic to the v_div_scale expansion with scale==1.
__device__ __forceinline__ float div_rn(float n, float d) {
    float r = __builtin_amdgcn_rcpf(d);
    float e = fmaf(-d, r, 1.0f);
    r = fmaf(e, r, r);                 // 1 Newton step on rcp
    float q = __fmul_rn(n, r);
    float s = fmaf(-d, q, n);          // exact residual
    q = fmaf(s, r, q);                 // correction 1
    s = fmaf(-d, q, n);
    q = fmaf(s, r, q);                 // correction 2 (div_fmas equivalent)
    return q;
}

// DPP cross-lane max stage on the VALU pipe (no LDS/DS traffic).
#define DPP_MAX_STAGE(x, ctrl)                                                   \
    do {                                                                         \
        int _yi = __builtin_amdgcn_update_dpp(__float_as_int(x),                 \
                                              __float_as_int(x), (ctrl),         \
                                              0xf, 0xf, false);                  \
        (x) = fmaxf((x), __int_as_float(_yi));                                   \
    } while (0)

// Full wave64 max; result valid in lane 63 (rows reduce, then bcast15/31 chain).
__device__ __forceinline__ float wave_max_lane63(float x) {
    DPP_MAX_STAGE(x, 0xB1);   // quad_perm [1,0,3,2]  (xor 1)
    DPP_MAX_STAGE(x, 0x4E);   // quad_perm [2,3,0,1]  (xor 2)
    DPP_MAX_STAGE(x, 0x141);  // row_half_mirror      (xor 4 after quads uniform)
    DPP_MAX_STAGE(x, 0x140);  // row_mirror           (xor 8 after 8-uniform)
    DPP_MAX_STAGE(x, 0x142);  // row_bcast15
    DPP_MAX_STAGE(x, 0x143);  // row_bcast31 -> lanes 48..63 hold full max
    return x;
}

// hpg[i] = 0 bits (+0.0f) and gt-area cache for all (b,g).
__global__ void k_init(const float* __restrict__ gt, unsigned int* __restrict__ hpg,
                       float* __restrict__ gab, int BG) {
    int i = blockIdx.x * 256 + threadIdx.x;
    if (i < BG) {
        hpg[i] = 0u;
        float4 gb = ((const float4*)gt)[i];
        gab[i] = box_area(gb.x, gb.y, gb.z, gb.w);
    }
}

// Pass 1: highest_per_gt. 4 anchors/thread, g-outer, DPP wave max, 1 LDS
// atomic per g per wave, one coalesced 64-wide global atomic per block.
// Grid: (ceil(A/1024), B), block 256.
__global__ __launch_bounds__(256, 8)
void pass1_hpg(const float* __restrict__ gt,
               const float* __restrict__ anchors,
               const float* __restrict__ gab,
               unsigned int* __restrict__ hpg, int A) {
    const int b = blockIdx.y;
    const int t = threadIdx.x;

    __shared__ unsigned int sred[G];
    if (t < G) sred[t] = 0u;
    __syncthreads();

    const int base = blockIdx.x * 1024;
    float ax1[4], ay1[4], ax2[4], ay2[4], aar[4];
#pragma unroll
    for (int k = 0; k < 4; ++k) {
        int a = base + k * 256 + t;
        bool v = (a < A);
        float4 ab = ((const float4*)anchors)[v ? a : 0];
        ax1[k] = v ? ab.x : -3.0e38f;   // degenerate -> inter==+0, q==+0
        ay1[k] = v ? ab.y : -3.0e38f;
        ax2[k] = v ? ab.z : -3.0e38f;
        ay2[k] = v ? ab.w : -3.0e38f;
        aar[k] = box_area(ax1[k], ay1[k], ax2[k], ay2[k]);
    }

    const float4* gtb = (const float4*)gt + (size_t)b * G;
    const float* gas = gab + b * G;
    unsigned int* hb = hpg + b * G;

#pragma unroll 4
    for (int g = 0; g < G; ++g) {
        const float4 gb = gtb[g];              // uniform -> s_load
        const float ga = gas[g];               // uniform -> s_load
        float m = 0.0f;
#pragma unroll
        for (int k = 0; k < 4; ++k) {          // 4 independent rcp/fma chains
            float inter = inter_area(gb.x, gb.y, gb.z, gb.w,
                                     ax1[k], ay1[k], ax2[k], ay2[k]);
            float denom = __fsub_rn(__fadd_rn(ga, aar[k]), inter);
            float q = div_rn(inter, denom);
            m = fmaxf(m, q);
        }
        m = wave_max_lane63(m);
        if ((t & 63) == 63)
            atomicMax(&sred[g], __float_as_uint(m));
    }
    __syncthreads();
    if (t < G) atomicMax(&hb[t], sred[t]);     // one coalesced line per block
}

// Pass 2 (R8 shape, proven): per anchor -> max/argmax over g, thresholds,
// low-quality recovery. gt/ga/hpg via uniform s_load; anchors per-lane.
// 2 anchors/thread. Grid: (ceil(A/512), B).
__global__ __launch_bounds__(256, 8)
void pass2_match(const float* __restrict__ gt,
                 const float* __restrict__ anchors,
                 const float* __restrict__ gab,
                 const unsigned int* __restrict__ hpg,
                 float* __restrict__ out_idx,
                 float* __restrict__ out_val, int A) {
    const int b = blockIdx.y;
    const int t = threadIdx.x;
    const int base = blockIdx.x * 512;

    float ax1[2], ay1[2], ax2[2], ay2[2], aar[2];
    bool val[2];
#pragma unroll
    for (int k = 0; k < 2; ++k) {
        int a = base + k * 256 + t;
        val[k] = (a < A);
        float4 ab = ((const float4*)anchors)[val[k] ? a : 0];
        ax1[k] = ab.x; ay1[k] = ab.y; ax2[k] = ab.z; ay2[k] = ab.w;
        aar[k] = box_area(ab.x, ab.y, ab.z, ab.w);
    }

    const float4* gtb = (const float4*)gt + (size_t)b * G;
    const float* gas = gab + b * G;
    const unsigned int* hpgb = hpg + b * G;

    // vmax=0/amax=0 start replicates np.argmax on an all-zero row (first idx);
    // strict > keeps the first max thereafter. q >= 0 always.
    float vmax[2] = {0.0f, 0.0f};
    int amax[2] = {0, 0};
    bool pu[2] = {false, false};
#pragma unroll 8
    for (int g = 0; g < G; ++g) {
        float4 gb = gtb[g];                        // uniform -> s_load
        float ga = gas[g];                         // uniform -> s_load
        float hg = __uint_as_float(hpgb[g]);       // uniform -> s_load
#pragma unroll
        for (int k = 0; k < 2; ++k) {
            float inter = inter_area(gb.x, gb.y, gb.z, gb.w,
                                     ax1[k], ay1[k], ax2[k], ay2[k]);
            float denom = __fsub_rn(__fadd_rn(ga, aar[k]), inter);
            float q = div_rn(inter, denom);
            pu[k] = pu[k] | (q == hg);
            if (q > vmax[k]) { vmax[k] = q; amax[k] = g; }  // first-max tie-break
        }
    }

#pragma unroll
    for (int k = 0; k < 2; ++k) {
        if (!val[k]) continue;
        int m;
        if (pu[k]) {
            m = amax[k];                    // low-quality match recovery
        } else if (vmax[k] < 0.4f) {
            m = -1;                         // BELOW_LOW_QUALITY
        } else if (vmax[k] < 0.5f) {
            m = -2;                         // BETWEEN_THRESHOLDS
        } else {
            m = amax[k];
        }
        size_t o = (size_t)b * A + (base + k * 256 + t);
        out_idx[o] = (float)m;
        out_val[o] = vmax[k];
    }
}

extern "C" void kernel_launch(void* const* d_in, const int* in_sizes, int n_in,
                              void* d_out, int out_size, void* d_ws, size_t ws_size,
                              hipStream_t stream) {
    const float* gt = (const float*)d_in[0];
    const float* anchors = (const float*)d_in[1];
    const int BG = in_sizes[0] / 4;   // B*G = 512
    const int B = BG / G;             // 8
    const int A = in_sizes[1] / 4;    // 120000

    // ws layout (u32 units): [0,512) hpg | [512,1024) ga cache
    unsigned int* hpg = (unsigned int*)d_ws;
    float* gab = (float*)d_ws + 512;

    float* out_idx = (float*)d_out;
    float* out_val = out_idx + (size_t)B * A;

    k_init<<<(BG + 255) / 256, 256, 0, stream>>>(gt, hpg, gab, BG);

    dim3 g1((A + 1023) / 1024, B);
    pass1_hpg<<<g1, 256, 0, stream>>>(gt, anchors, gab, hpg, A);

    dim3 g2((A + 511) / 512, B);
    pass2_match<<<g2, 256, 0, stream>>>(gt, anchors, gab, hpg, out_idx, out_val, A);
}